// Round 9
// baseline (4428.837 us; speedup 1.0000x reference)
//
#include <hip/hip_runtime.h>

#define TT 2048
#define LL 50
#define DD 300
#define HH 100
#define NCC 7

typedef unsigned short u16;
typedef unsigned int u32;
typedef _Float16 f16x2 __attribute__((ext_vector_type(2)));

__device__ __forceinline__ u32 fkey(float f){ u32 u; __builtin_memcpy(&u, &f, 4); return (u & 0x80000000u) ? ~u : (u | 0x80000000u); }
__device__ __forceinline__ float funkey(u32 k){ u32 u = (k & 0x80000000u) ? (k & 0x7FFFFFFFu) : ~k; float f; __builtin_memcpy(&f, &u, 4); return f; }
__device__ __forceinline__ float frcp(float x){ return __builtin_amdgcn_rcpf(x); }
__device__ __forceinline__ float sigm(float x){ return frcp(1.f + __expf(-x)); }
__device__ __forceinline__ float ftanh(float x){ return 1.f - 2.f * frcp(1.f + __expf(2.f * x)); }

#if defined(__has_builtin)
#if __has_builtin(__builtin_amdgcn_fdot2)
#define HAS_FDOT2 1
#endif
#endif
__device__ __forceinline__ float fdot2(f16x2 a, f16x2 b, float c){
#ifdef HAS_FDOT2
  return __builtin_amdgcn_fdot2(a, b, c, false);
#else
  return c + (float)a.x * (float)b.x + (float)a.y * (float)b.y;
#endif
}
__device__ __forceinline__ f16x2 pk(float x, float y){ f16x2 r; r.x = (_Float16)x; r.y = (_Float16)y; return r; }

__device__ __forceinline__ u32 ld_acq(u32* p){ return __hip_atomic_load(p, __ATOMIC_ACQUIRE, __HIP_MEMORY_SCOPE_AGENT); }
__device__ __forceinline__ void st_rel(u32* p, u32 v){ __hip_atomic_store(p, v, __ATOMIC_RELEASE, __HIP_MEMORY_SCOPE_AGENT); }

// ---------------- Kernel 1: embedding + TextCNN(3,4,5) + max-relu + s_utt ----------------
#define WROW 304
__device__ __forceinline__ int widx(int pos, int d){ return pos * WROW + (pos >> 3) * 4 + d; }
#define WSZ (52 * WROW + 7 * 4)

__global__ __launch_bounds__(256) void k_cnn(const int* __restrict__ sents,
    const float* __restrict__ emb,
    const float* __restrict__ Wc3, const float* __restrict__ bc3,
    const float* __restrict__ Wc4, const float* __restrict__ bc4,
    const float* __restrict__ Wc5, const float* __restrict__ bc5,
    const float* __restrict__ Wt,  const float* __restrict__ bt,
    float* __restrict__ su)
{
  __shared__ float w[WSZ];
  __shared__ int ids[LL];
  __shared__ u32 feats_u[192];
  const int tid = threadIdx.x;
  const int s = blockIdx.x;

  if (tid < LL) ids[tid] = sents[s * LL + tid];
  for (int e = tid; e < WSZ; e += 256) w[e] = 0.f;
  if (tid < 192) feats_u[tid] = 0u;
  __syncthreads();
  for (int e = tid; e < LL * 75; e += 256){
    int l = e / 75, d4 = (e - l * 75) * 4;
    *(float4*)&w[widx(l, d4)] = *(const float4*)&emb[(size_t)ids[l] * DD + d4];
  }
  __syncthreads();

  for (int task = tid; task < 288; task += 256){
    int F  = task / 6;
    int pc = task - F * 6;
    int kk, fbase, colbase; const float* W;
    if (F < 16){ kk = 3; fbase = F * 4;         W = Wc3; colbase = fbase; }
    else if (F < 32){ kk = 4; fbase = (F-16)*4; W = Wc4; colbase = 64 + fbase; }
    else { kk = 5; fbase = (F-32)*4;            W = Wc5; colbase = 128 + fbase; }
    int pos0 = pc * 8;
    float acc[4][8];
    #pragma unroll
    for (int fi = 0; fi < 4; ++fi)
      #pragma unroll
      for (int p = 0; p < 8; ++p) acc[fi][p] = 0.f;

    for (int j = 0; j < kk; ++j){
      const float* wr = W + (size_t)(fbase * kk + j) * DD;
      int rb[8];
      #pragma unroll
      for (int p = 0; p < 8; ++p) rb[p] = widx(pos0 + p + j, 0);
      for (int d = 0; d < DD; d += 4){
        float4 a[8];
        #pragma unroll
        for (int p = 0; p < 8; ++p) a[p] = *(const float4*)&w[rb[p] + d];
        #pragma unroll
        for (int fi = 0; fi < 4; ++fi){
          float4 wv = *(const float4*)(wr + (size_t)fi * kk * DD + d);
          #pragma unroll
          for (int p = 0; p < 8; ++p)
            acc[fi][p] += a[p].x * wv.x + a[p].y * wv.y + a[p].z * wv.z + a[p].w * wv.w;
        }
      }
    }
    int Pk = LL - kk + 1;
    #pragma unroll
    for (int fi = 0; fi < 4; ++fi){
      float m = -1e30f;
      #pragma unroll
      for (int p = 0; p < 8; ++p) if (pos0 + p < Pk) m = fmaxf(m, acc[fi][p]);
      atomicMax(&feats_u[colbase + fi], fkey(m));
    }
  }
  __syncthreads();
  if (tid < 192){
    float m = funkey(feats_u[tid]);
    float bias = (tid < 64) ? bc3[tid] : ((tid < 128) ? bc4[tid - 64] : bc5[tid - 128]);
    feats_u[tid] = __float_as_uint(fmaxf(0.f, m + bias));
  }
  __syncthreads();
  if (tid < HH){
    float acc = bt[tid];
    for (int c = 0; c < 192; ++c)
      acc += __uint_as_float(feats_u[c]) * Wt[c * HH + tid];
    su[(size_t)s * HH + tid] = ftanh(acc);
  }
}

// ================= Fused pipeline kernel =================
// grid = 256 blocks x 320 threads (<= #CUs, all co-resident -> spin-waits safe).
// Block 0: sequential GRU scan producer (round-5 structure, best measured),
//          gated per 16-step chunk on gic flags, releases hid_prog.
// Blocks 1..255: job queue via global ticket:
//   job 0          : row-0 classifier (needs su only)
//   jobs 1..128    : gi_c chunk k (gic rows 16k..) -> sets gic flag
//   jobs 129..256  : gi_m chunk k (gm rows, gated on hid_prog) -> sets gm flag
//   jobs 257..2303 : attention query q = jid-257 (gated on gm flags) + fused cls
// ctrl layout (u32, in ws): [0]=ticket [1]=hid_prog [8..135]=gic flags [136..263]=gm flags
#define NJOBS 2304
#define LDS_RAW 52640
// att offsets
#define A_MEML   0
#define A_MEM16  16640
#define A_GL     24960
#define A_GHL    48960
#define A_BIL    50160
#define A_QL     51360
#define A_HBUF   51776
#define A_HB16   52176
#define A_SCL    52384
#define JOBSLOT  52608
// scan offsets
#define S_GIBUF  0
#define S_HIDBUF 19200
#define S_HA     25600
#define S_HB     25808

__global__ __launch_bounds__(320) void k_fused(
    const float* __restrict__ su, float* __restrict__ gic,
    float* __restrict__ hid, float* __restrict__ gmw,
    u32* __restrict__ ctrl,
    const float* __restrict__ Wih_c, const float* __restrict__ bih_c,
    const float* __restrict__ Whh_c, const float* __restrict__ bhh_c,
    const float* __restrict__ Wih_m, const float* __restrict__ bih_m,
    const float* __restrict__ Whh_m, const float* __restrict__ bhh_m,
    const float* __restrict__ Wcls,  const float* __restrict__ bcls,
    float* __restrict__ out)
{
  __shared__ __attribute__((aligned(16))) unsigned char raw[LDS_RAW];
  const int tid = threadIdx.x;
  const int steps = TT - 1;

  if (blockIdx.x == 0){
    // ---------------- producer: context-GRU scan ----------------
    float* gi_buf  = (float*)(raw + S_GIBUF);
    float* hid_buf = (float*)(raw + S_HIDBUF);
    _Float16* hA = (_Float16*)(raw + S_HA);
    _Float16* hB = (_Float16*)(raw + S_HB);
    f16x2 wr[52], wz[52], wn[52];
    float br = 0.f, bz = 0.f, bn = 0.f, hreg = 0.f;
    if (tid < HH){
      const float* r0 = Whh_c + (size_t)tid * 100;
      const float* r1 = Whh_c + (size_t)(tid + 100) * 100;
      const float* r2 = Whh_c + (size_t)(tid + 200) * 100;
      #pragma unroll
      for (int i = 0; i < 25; ++i){
        float4 a;
        a = *(const float4*)(r0 + 4*i); wr[2*i] = pk(a.x,a.y); wr[2*i+1] = pk(a.z,a.w);
        a = *(const float4*)(r1 + 4*i); wz[2*i] = pk(a.x,a.y); wz[2*i+1] = pk(a.z,a.w);
        a = *(const float4*)(r2 + 4*i); wn[2*i] = pk(a.x,a.y); wn[2*i+1] = pk(a.z,a.w);
      }
      br = bhh_c[tid]; bz = bhh_c[tid + 100]; bn = bhh_c[tid + 200];
    }
    #pragma unroll
    for (int i = 50; i < 52; ++i){ wr[i] = pk(0,0); wz[i] = pk(0,0); wn[i] = pk(0,0); }
    if (tid < 104){ hA[tid] = (_Float16)0.f; hB[tid] = (_Float16)0.f; }

    int t0 = 0, chunk = 0;
    while (t0 < steps){
      int cnt = steps - t0; if (cnt > 16) cnt = 16;
      // wait for gic chunk, then stage into LDS
      while (ld_acq(&ctrl[8 + chunk]) == 0) __builtin_amdgcn_s_sleep(8);
      for (int e = tid; e < cnt * 75; e += 320)
        ((float4*)gi_buf)[e] = ((const float4*)(gic + (size_t)t0 * 300))[e];
      __syncthreads();
      for (int s = 0; s < cnt; ++s){
        const _Float16* hs = ((t0 + s) & 1) ? hB : hA;
        _Float16*       hd = ((t0 + s) & 1) ? hA : hB;
        if (tid < HH){
          float ar0=0, ar1=0, az0=0, az1=0, an0=0, an1=0;
          const float4* hq = (const float4*)hs;
          #pragma unroll
          for (int g = 0; g < 13; ++g){
            float4 hv = hq[g];
            f16x2 p0 = __builtin_bit_cast(f16x2, hv.x), p1 = __builtin_bit_cast(f16x2, hv.y);
            f16x2 p2 = __builtin_bit_cast(f16x2, hv.z), p3 = __builtin_bit_cast(f16x2, hv.w);
            ar0 = fdot2(wr[4*g  ], p0, ar0); ar1 = fdot2(wr[4*g+1], p1, ar1);
            az0 = fdot2(wz[4*g  ], p0, az0); az1 = fdot2(wz[4*g+1], p1, az1);
            an0 = fdot2(wn[4*g  ], p0, an0); an1 = fdot2(wn[4*g+1], p1, an1);
            ar0 = fdot2(wr[4*g+2], p2, ar0); ar1 = fdot2(wr[4*g+3], p3, ar1);
            az0 = fdot2(wz[4*g+2], p2, az0); az1 = fdot2(wz[4*g+3], p3, az1);
            an0 = fdot2(wn[4*g+2], p2, an0); an1 = fdot2(wn[4*g+3], p3, an1);
          }
          const float* gp = gi_buf + s * 300;
          float r = sigm(gp[tid]       + br + ar0 + ar1);
          float z = sigm(gp[tid + 100] + bz + az0 + az1);
          float n = ftanh(gp[tid + 200] + r * (bn + an0 + an1));
          float o = (1.f - z) * n + z * hreg;
          hreg = o;
          hd[tid] = (_Float16)o;
          hid_buf[s * HH + tid] = o;
        }
        __syncthreads();
      }
      // flush hid chunk, release progress
      for (int e = tid; e < cnt * 25; e += 320)
        ((float4*)(hid + (size_t)t0 * HH))[e] = ((const float4*)hid_buf)[e];
      __syncthreads();
      if (tid == 0) st_rel(&ctrl[1], (u32)(t0 + cnt));
      t0 += cnt; ++chunk;
    }
    return;
  }

  // ---------------- consumers ----------------
  u32* jobslot = (u32*)(raw + JOBSLOT);
  for (;;){
    __syncthreads();
    if (tid == 0) *jobslot = atomicAdd(&ctrl[0], 1u);
    __syncthreads();
    u32 jid = *jobslot;
    if (jid >= NJOBS) break;

    if (jid == 0){
      // row-0 classifier: out[0] = log_softmax(su[0] @ Wcls + bcls)
      float* tmpf = (float*)(raw + A_SCL);
      if (tid < NCC){
        float acc = bcls[tid];
        for (int h = 0; h < HH; ++h) acc += su[h] * Wcls[h * NCC + tid];
        tmpf[tid] = acc;
      }
      __syncthreads();
      if (tid < NCC){
        float m = tmpf[0];
        #pragma unroll
        for (int c = 1; c < NCC; ++c) m = fmaxf(m, tmpf[c]);
        float ss = 0.f;
        #pragma unroll
        for (int c = 0; c < NCC; ++c) ss += __expf(tmpf[c] - m);
        out[tid] = tmpf[tid] - (m + __logf(ss));
      }
      continue;
    }

    if (jid <= 256){
      // gi chunk: gic (jid 1..128, from su) or gm (jid 129..256, from hid, gated)
      bool is_c = (jid <= 128);
      int k = is_c ? (int)jid - 1 : (int)jid - 129;
      int r0 = k * 16, cnt = steps - r0; if (cnt > 16) cnt = 16;
      if (!is_c){
        u32 need = (u32)(r0 + cnt);
        while (ld_acq(&ctrl[1]) < need) __builtin_amdgcn_s_sleep(8);
      }
      const float* srcG = (is_c ? su : hid) + (size_t)r0 * HH;
      float*       dst  = (is_c ? gic : gmw) + (size_t)r0 * 300;
      const float* W    = is_c ? Wih_c : Wih_m;
      const float* B    = is_c ? bih_c : bih_m;
      float* sbuf = (float*)raw;
      for (int e = tid; e < cnt * 25; e += 320)
        ((float4*)sbuf)[e] = ((const float4*)srcG)[e];
      __syncthreads();
      if (tid < 300){
        float4 wv[25];
        const float* wrp = W + (size_t)tid * HH;
        #pragma unroll
        for (int i = 0; i < 25; ++i) wv[i] = *(const float4*)(wrp + 4 * i);
        float b = B[tid];
        for (int r = 0; r < cnt; ++r){
          float a0 = 0, a1 = 0, a2 = 0, a3 = 0;
          const float* xr = sbuf + r * HH;
          #pragma unroll
          for (int i = 0; i < 25; ++i){
            float4 xv = *(const float4*)(xr + 4 * i);
            a0 += xv.x * wv[i].x; a1 += xv.y * wv[i].y;
            a2 += xv.z * wv[i].z; a3 += xv.w * wv[i].w;
          }
          dst[(size_t)r * 300 + tid] = (a0 + a1) + (a2 + a3) + b;
        }
      }
      __syncthreads();
      if (tid == 0) st_rel(&ctrl[(is_c ? 8 : 136) + k], 1u);
      continue;
    }

    // ---------------- attention query q + fused classifier ----------------
    {
      int q = (int)jid - 257;
      int wmin = 39 - q; if (wmin < 0) wmin = 0;
      int clo = ((q >= 39) ? (q - 39) : 0) >> 4;
      int chi = q >> 4;
      for (int c = clo; c <= chi; ++c)
        while (ld_acq(&ctrl[136 + c]) == 0) __builtin_amdgcn_s_sleep(8);

      float*    mem_l = (float*)(raw + A_MEML);
      _Float16* mem16 = (_Float16*)(raw + A_MEM16);
      _Float16* g_l   = (_Float16*)(raw + A_GL);
      float*    gh_l  = (float*)(raw + A_GHL);
      float*    bi_l  = (float*)(raw + A_BIL);
      float*    q_l   = (float*)(raw + A_QL);
      float*    hbuf  = (float*)(raw + A_HBUF);
      _Float16* hb16  = (_Float16*)(raw + A_HB16);
      float*    sc_l  = (float*)(raw + A_SCL);
      f16x2 wreg[52];
      float bh = 0.f;

      if (tid < 300){ bi_l[tid] = bih_m[tid]; bh = bhh_m[tid]; }
      if (tid < 104) q_l[tid] = (tid < 100) ? su[(size_t)(q + 1) * HH + tid] : 0.f;
      for (int e = tid; e < 40 * 104; e += 320){
        int w = e / 104, i = e - w * 104;
        float v = 0.f;
        if (i < 100 && w >= wmin) v = hid[(size_t)(q - 39 + w) * HH + i];
        mem_l[e] = v;
        mem16[e] = (_Float16)v;
      }
      for (int e = tid; e < 40 * 300; e += 320){
        int w = e / 300, j = e - w * 300;
        float v = (w >= wmin) ? gmw[(size_t)(q - 39 + w) * 300 + j] : 0.f;
        g_l[e] = (_Float16)v;
      }
      if (tid < 300){
        const float* r0 = Whh_m + (size_t)tid * 100;
        #pragma unroll
        for (int i = 0; i < 25; ++i){
          float4 a = *(const float4*)(r0 + 4 * i);
          wreg[2*i] = pk(a.x, a.y); wreg[2*i+1] = pk(a.z, a.w);
        }
      }
      wreg[50] = pk(0,0); wreg[51] = pk(0,0);
      __syncthreads();

      for (int hop = 0; hop < 3; ++hop){
        if (tid < 40){
          float a0 = 0, a1 = 0, a2 = 0, a3 = 0;
          const float* mr = &mem_l[tid * 104];
          #pragma unroll
          for (int i = 0; i < 25; ++i){
            float4 m4 = *(const float4*)&mr[4 * i];
            float4 q4 = *(const float4*)&q_l[4 * i];
            a0 += m4.x * q4.x; a1 += m4.y * q4.y; a2 += m4.z * q4.z; a3 += m4.w * q4.w;
          }
          sc_l[tid] = (tid >= wmin) ? ((a0 + a1) + (a2 + a3)) : -1e10f;
        }
        __syncthreads();
        if (tid < 64){
          float v = (tid < 40) ? sc_l[tid] : -3e38f;
          float m = v;
          #pragma unroll
          for (int off = 32; off; off >>= 1) m = fmaxf(m, __shfl_xor(m, off));
          float e = (tid < 40) ? __expf(v - m) : 0.f;
          float ssum = e;
          #pragma unroll
          for (int off = 32; off; off >>= 1) ssum += __shfl_xor(ssum, off);
          if (tid < 40) sc_l[tid] = e * frcp(ssum);
        }
        __syncthreads();
        if (tid < 50){
          float c0 = 0.f, c1 = 0.f;
          for (int w = wmin; w < 40; ++w){
            float a = sc_l[w];
            float2 mv = *(const float2*)&mem_l[w * 104 + 2 * tid];
            c0 += a * mv.x; c1 += a * mv.y;
          }
          float q0 = ftanh(q_l[2 * tid]     + c0);
          float q1 = ftanh(q_l[2 * tid + 1] + c1);
          *(float2*)&q_l[2 * tid] = make_float2(q0, q1);
        }
        if (hop == 2) break;

        if (hop == 1){
          if (tid < 300){
            const float* r0 = Wih_m + (size_t)tid * 100;
            #pragma unroll
            for (int i = 0; i < 25; ++i){
              float4 a = *(const float4*)(r0 + 4 * i);
              wreg[2*i] = pk(a.x, a.y); wreg[2*i+1] = pk(a.z, a.w);
            }
            for (int w = 0; w < 40; ++w){
              float a0 = 0, a1 = 0;
              const float4* mq = (const float4*)&mem16[w * 104];
              #pragma unroll
              for (int g = 0; g < 13; ++g){
                float4 hv = mq[g];
                a0 = fdot2(wreg[4*g  ], __builtin_bit_cast(f16x2, hv.x), a0);
                a1 = fdot2(wreg[4*g+1], __builtin_bit_cast(f16x2, hv.y), a1);
                a0 = fdot2(wreg[4*g+2], __builtin_bit_cast(f16x2, hv.z), a0);
                a1 = fdot2(wreg[4*g+3], __builtin_bit_cast(f16x2, hv.w), a1);
              }
              g_l[w * 300 + tid] = (_Float16)(a0 + a1 + bi_l[tid]);
            }
            const float* rh = Whh_m + (size_t)tid * 100;
            #pragma unroll
            for (int i = 0; i < 25; ++i){
              float4 a = *(const float4*)(rh + 4 * i);
              wreg[2*i] = pk(a.x, a.y); wreg[2*i+1] = pk(a.z, a.w);
            }
          }
        }

        if (tid < HH) hbuf[tid] = 0.f;
        if (tid < 104) hb16[tid] = (_Float16)0.f;
        __syncthreads();
        for (int w = 0; w < 40; ++w){
          if (tid < 300){
            float a0 = 0, a1 = 0;
            const float4* hq = (const float4*)hb16;
            #pragma unroll
            for (int g = 0; g < 13; ++g){
              float4 hv = hq[g];
              a0 = fdot2(wreg[4*g  ], __builtin_bit_cast(f16x2, hv.x), a0);
              a1 = fdot2(wreg[4*g+1], __builtin_bit_cast(f16x2, hv.y), a1);
              a0 = fdot2(wreg[4*g+2], __builtin_bit_cast(f16x2, hv.z), a0);
              a1 = fdot2(wreg[4*g+3], __builtin_bit_cast(f16x2, hv.w), a1);
            }
            gh_l[tid] = a0 + a1 + bh;
          }
          __syncthreads();
          if (tid < HH){
            float o = hbuf[tid];
            if (w >= wmin){
              const _Float16* gp = &g_l[w * 300];
              float gir = (float)gp[tid], giz = (float)gp[tid + 100], gin = (float)gp[tid + 200];
              float r = sigm(gir + gh_l[tid]);
              float z = sigm(giz + gh_l[tid + 100]);
              float n = ftanh(gin + r * gh_l[tid + 200]);
              o = (1.f - z) * n + z * o;
            }
            hbuf[tid] = o;
            hb16[tid] = (_Float16)o;
            mem_l[w * 104 + tid] = o;
            mem16[w * 104 + tid] = (_Float16)o;
          }
          __syncthreads();
        }
      }
      // fused classifier epilogue
      __syncthreads();
      if (tid < NCC){
        float acc = bcls[tid];
        for (int h = 0; h < HH; ++h) acc += q_l[h] * Wcls[h * NCC + tid];
        sc_l[tid] = acc;
      }
      __syncthreads();
      if (tid < NCC){
        float m = sc_l[0];
        #pragma unroll
        for (int c = 1; c < NCC; ++c) m = fmaxf(m, sc_l[c]);
        float ss = 0.f;
        #pragma unroll
        for (int c = 0; c < NCC; ++c) ss += __expf(sc_l[c] - m);
        out[(size_t)(q + 1) * NCC + tid] = sc_l[tid] - (m + __logf(ss));
      }
    }
  }
}

extern "C" void kernel_launch(void* const* d_in, const int* in_sizes, int n_in,
                              void* d_out, int out_size, void* d_ws, size_t ws_size,
                              hipStream_t stream)
{
  const int* sents  = (const int*)d_in[0];
  // d_in[1] = lengths (unused by the reference)
  const float* emb    = (const float*)d_in[2];
  const float* Wc3    = (const float*)d_in[3];  const float* bc3 = (const float*)d_in[4];
  const float* Wc4    = (const float*)d_in[5];  const float* bc4 = (const float*)d_in[6];
  const float* Wc5    = (const float*)d_in[7];  const float* bc5 = (const float*)d_in[8];
  const float* Wt     = (const float*)d_in[9];  const float* bt  = (const float*)d_in[10];
  const float* Wih_c  = (const float*)d_in[11]; const float* Whh_c = (const float*)d_in[12];
  const float* bih_c  = (const float*)d_in[13]; const float* bhh_c = (const float*)d_in[14];
  const float* Wih_m  = (const float*)d_in[15]; const float* Whh_m = (const float*)d_in[16];
  const float* bih_m  = (const float*)d_in[17]; const float* bhh_m = (const float*)d_in[18];
  const float* Wcls   = (const float*)d_in[19]; const float* bcls  = (const float*)d_in[20];

  float* ws    = (float*)d_ws;
  float* su    = ws;                  // 2048*100 = 204800
  float* gic   = su  + 204800;        // 2047*300 = 614100
  float* hid   = gic + 614100;        // 2047*100 = 204700
  float* gmw   = hid + 204700;        // 2047*300 = 614100
  u32*   ctrl  = (u32*)(gmw + 614100);// 512 u32 control region

  hipMemsetAsync((void*)ctrl, 0, 2048, stream);
  k_cnn  <<<TT,  256, 0, stream>>>(sents, emb, Wc3, bc3, Wc4, bc4, Wc5, bc5, Wt, bt, su);
  k_fused<<<256, 320, 0, stream>>>(su, gic, hid, gmw, ctrl,
                                   Wih_c, bih_c, Whh_c, bhh_c,
                                   Wih_m, bih_m, Whh_m, bhh_m,
                                   Wcls, bcls, (float*)d_out);
}

// Round 10
// 3831.461 us; speedup vs baseline: 1.1559x; 1.1559x over previous
//
#include <hip/hip_runtime.h>

#define TT 2048
#define LL 50
#define DD 300
#define HH 100
#define NCC 7
#define STEPS (TT - 1)

typedef unsigned short u16;
typedef unsigned int u32;
typedef _Float16 f16x2 __attribute__((ext_vector_type(2)));

__device__ __forceinline__ u32 fkey(float f){ u32 u; __builtin_memcpy(&u, &f, 4); return (u & 0x80000000u) ? ~u : (u | 0x80000000u); }
__device__ __forceinline__ float funkey(u32 k){ u32 u = (k & 0x80000000u) ? (k & 0x7FFFFFFFu) : ~k; float f; __builtin_memcpy(&f, &u, 4); return f; }
__device__ __forceinline__ float frcp(float x){ return __builtin_amdgcn_rcpf(x); }
__device__ __forceinline__ float sigm(float x){ return frcp(1.f + __expf(-x)); }
__device__ __forceinline__ float ftanh(float x){ return 1.f - 2.f * frcp(1.f + __expf(2.f * x)); }

#if defined(__has_builtin)
#if __has_builtin(__builtin_amdgcn_fdot2)
#define HAS_FDOT2 1
#endif
#endif
__device__ __forceinline__ float fdot2(f16x2 a, f16x2 b, float c){
#ifdef HAS_FDOT2
  return __builtin_amdgcn_fdot2(a, b, c, false);
#else
  return c + (float)a.x * (float)b.x + (float)a.y * (float)b.y;
#endif
}
__device__ __forceinline__ f16x2 pk(float x, float y){ f16x2 r; r.x = (_Float16)x; r.y = (_Float16)y; return r; }

// relaxed polling; ONE acquire fence per wait event (leader), not per poll
__device__ __forceinline__ u32 ld_rlx(u32* p){ return __hip_atomic_load(p, __ATOMIC_RELAXED, __HIP_MEMORY_SCOPE_AGENT); }
__device__ __forceinline__ void st_rel(u32* p, u32 v){ __hip_atomic_store(p, v, __ATOMIC_RELEASE, __HIP_MEMORY_SCOPE_AGENT); }
__device__ __forceinline__ void wait_ge(u32* p, u32 need, int tid){
  if (tid == 0){
    while (ld_rlx(p) < need) __builtin_amdgcn_s_sleep(16);
    __builtin_amdgcn_fence(__ATOMIC_ACQUIRE, "agent");
  }
  __syncthreads();
}

// ---- LDS layout (union, bytes) ----
#define LDS_RAW 64520
// attention job
#define A_MEML   0
#define A_MEM16  16640
#define A_GL     24960
#define A_GHL    48960
#define A_BIL    50160
#define A_QL     51360
#define A_HBUF   51776
#define A_HB16   52176
#define A_SCL    52384
// cnn job
#define C_W      0
#define C_IDS    63344
#define C_FEATS  63552
#define JOBSLOT  64512
// scan producer
#define S_GIBUF  0
#define S_HIDBUF 19200
#define S_HA     25600
#define S_HB     25808
// cnn LDS tile geometry
#define WROW 304
__device__ __forceinline__ int widx(int pos, int d){ return pos * WROW + (pos >> 3) * 4 + d; }
#define WSZF (52 * WROW + 7 * 4)   // floats

// ---- ctrl indices (u32) ----
#define CT_TICKET 0
#define CT_HPROG  1
#define CT_GIC    8
#define CT_GM     136
#define CT_SUF    264
#define CT_SUC    392
// jobs: [0..2047]=cnn sentence, 2048=row-0 classifier, [2049..4095]=att q=jid-2049
#define NJOBS 4096

__global__ __launch_bounds__(320, 2) void k_fused(
    const int* __restrict__ sents, const float* __restrict__ emb,
    const float* __restrict__ Wc3, const float* __restrict__ bc3,
    const float* __restrict__ Wc4, const float* __restrict__ bc4,
    const float* __restrict__ Wc5, const float* __restrict__ bc5,
    const float* __restrict__ Wt,  const float* __restrict__ bt,
    float* __restrict__ su, float* __restrict__ gic,
    float* __restrict__ hid, float* __restrict__ gmw,
    u32* __restrict__ ctrl,
    const float* __restrict__ Wih_c, const float* __restrict__ bih_c,
    const float* __restrict__ Whh_c, const float* __restrict__ bhh_c,
    const float* __restrict__ Wih_m, const float* __restrict__ bih_m,
    const float* __restrict__ Whh_m, const float* __restrict__ bhh_m,
    const float* __restrict__ Wcls,  const float* __restrict__ bcls,
    float* __restrict__ out)
{
  __shared__ __attribute__((aligned(16))) unsigned char raw[LDS_RAW];
  const int tid = threadIdx.x;
  const int bid = blockIdx.x;

  // ================= block 0: context-GRU scan producer =================
  if (bid == 0){
    float* gi_buf  = (float*)(raw + S_GIBUF);
    float* hid_buf = (float*)(raw + S_HIDBUF);
    _Float16* hA = (_Float16*)(raw + S_HA);
    _Float16* hB = (_Float16*)(raw + S_HB);
    f16x2 wr[52], wz[52], wn[52];
    float br = 0.f, bz = 0.f, bn = 0.f, hreg = 0.f;
    if (tid < HH){
      const float* r0 = Whh_c + (size_t)tid * 100;
      const float* r1 = Whh_c + (size_t)(tid + 100) * 100;
      const float* r2 = Whh_c + (size_t)(tid + 200) * 100;
      #pragma unroll
      for (int i = 0; i < 25; ++i){
        float4 a;
        a = *(const float4*)(r0 + 4*i); wr[2*i] = pk(a.x,a.y); wr[2*i+1] = pk(a.z,a.w);
        a = *(const float4*)(r1 + 4*i); wz[2*i] = pk(a.x,a.y); wz[2*i+1] = pk(a.z,a.w);
        a = *(const float4*)(r2 + 4*i); wn[2*i] = pk(a.x,a.y); wn[2*i+1] = pk(a.z,a.w);
      }
      br = bhh_c[tid]; bz = bhh_c[tid + 100]; bn = bhh_c[tid + 200];
    }
    #pragma unroll
    for (int i = 50; i < 52; ++i){ wr[i] = pk(0,0); wz[i] = pk(0,0); wn[i] = pk(0,0); }
    if (tid < 104){ hA[tid] = (_Float16)0.f; hB[tid] = (_Float16)0.f; }

    int t0 = 0, chunk = 0;
    while (t0 < STEPS){
      int cnt = STEPS - t0; if (cnt > 16) cnt = 16;
      wait_ge(&ctrl[CT_GIC + chunk], 1u, tid);
      for (int e = tid; e < cnt * 75; e += 320)
        ((float4*)gi_buf)[e] = ((const float4*)(gic + (size_t)t0 * 300))[e];
      __syncthreads();
      for (int s = 0; s < cnt; ++s){
        const _Float16* hs = ((t0 + s) & 1) ? hB : hA;
        _Float16*       hd = ((t0 + s) & 1) ? hA : hB;
        if (tid < HH){
          float ar0=0, ar1=0, az0=0, az1=0, an0=0, an1=0;
          const float4* hq = (const float4*)hs;
          #pragma unroll
          for (int g = 0; g < 13; ++g){
            float4 hv = hq[g];
            f16x2 p0 = __builtin_bit_cast(f16x2, hv.x), p1 = __builtin_bit_cast(f16x2, hv.y);
            f16x2 p2 = __builtin_bit_cast(f16x2, hv.z), p3 = __builtin_bit_cast(f16x2, hv.w);
            ar0 = fdot2(wr[4*g  ], p0, ar0); ar1 = fdot2(wr[4*g+1], p1, ar1);
            az0 = fdot2(wz[4*g  ], p0, az0); az1 = fdot2(wz[4*g+1], p1, az1);
            an0 = fdot2(wn[4*g  ], p0, an0); an1 = fdot2(wn[4*g+1], p1, an1);
            ar0 = fdot2(wr[4*g+2], p2, ar0); ar1 = fdot2(wr[4*g+3], p3, ar1);
            az0 = fdot2(wz[4*g+2], p2, az0); az1 = fdot2(wz[4*g+3], p3, az1);
            an0 = fdot2(wn[4*g+2], p2, an0); an1 = fdot2(wn[4*g+3], p3, an1);
          }
          const float* gp = gi_buf + s * 300;
          float r = sigm(gp[tid]       + br + ar0 + ar1);
          float z = sigm(gp[tid + 100] + bz + az0 + az1);
          float n = ftanh(gp[tid + 200] + r * (bn + an0 + an1));
          float o = (1.f - z) * n + z * hreg;
          hreg = o;
          hd[tid] = (_Float16)o;
          hid_buf[s * HH + tid] = o;
        }
        __syncthreads();
      }
      for (int e = tid; e < cnt * 25; e += 320)
        ((float4*)(hid + (size_t)t0 * HH))[e] = ((const float4*)hid_buf)[e];
      __syncthreads();
      if (tid == 0) st_rel(&ctrl[CT_HPROG], (u32)(t0 + cnt));
      t0 += cnt; ++chunk;
    }
    return;
  }

  // ================= blocks 1-3: gi servers (1,2 = gic even/odd; 3 = gm) =================
  if (bid <= 3){
    const bool is_c = (bid <= 2);
    const int k0 = is_c ? (bid - 1) : 0;
    const int ks = is_c ? 2 : 1;
    const float* W = is_c ? Wih_c : Wih_m;
    const float* B = is_c ? bih_c : bih_m;
    const float* src = is_c ? su : hid;
    float* dst = is_c ? gic : gmw;
    u32* flags = ctrl + (is_c ? CT_GIC : CT_GM);
    float4 wv[25]; float bb = 0.f;
    if (tid < 300){
      const float* wrp = W + (size_t)tid * HH;
      #pragma unroll
      for (int i = 0; i < 25; ++i) wv[i] = *(const float4*)(wrp + 4 * i);
      bb = B[tid];
    }
    float* sbuf = (float*)raw;
    for (int k = k0; k < 128; k += ks){
      int r0 = k * 16, cnt = STEPS - r0; if (cnt > 16) cnt = 16;
      if (is_c) wait_ge(&ctrl[CT_SUF + k], 1u, tid);           // su group k ready
      else      wait_ge(&ctrl[CT_HPROG], (u32)(r0 + cnt), tid); // hid rows ready
      for (int e = tid; e < cnt * 25; e += 320)
        ((float4*)sbuf)[e] = ((const float4*)(src + (size_t)r0 * HH))[e];
      __syncthreads();
      if (tid < 300){
        for (int r = 0; r < cnt; ++r){
          float a0 = 0, a1 = 0, a2 = 0, a3 = 0;
          const float* xr = sbuf + r * HH;
          #pragma unroll
          for (int i = 0; i < 25; ++i){
            float4 xv = *(const float4*)(xr + 4 * i);
            a0 += xv.x * wv[i].x; a1 += xv.y * wv[i].y;
            a2 += xv.z * wv[i].z; a3 += xv.w * wv[i].w;
          }
          dst[(size_t)(r0 + r) * 300 + tid] = (a0 + a1) + (a2 + a3) + bb;
        }
      }
      __syncthreads();
      if (tid == 0) st_rel(&flags[k], 1u);
    }
    return;
  }

  // ================= blocks 4..255: ticket consumers =================
  u32* jobslot = (u32*)(raw + JOBSLOT);
  for (;;){
    __syncthreads();
    if (tid == 0) *jobslot = atomicAdd(&ctrl[CT_TICKET], 1u);
    __syncthreads();
    u32 jid = *jobslot;
    if (jid >= NJOBS) break;

    if (jid < 2048){
      // ---- cnn job: sentence s ----
      int s = (int)jid;
      float* w = (float*)(raw + C_W);
      int* ids = (int*)(raw + C_IDS);
      u32* feats_u = (u32*)(raw + C_FEATS);
      if (tid < LL) ids[tid] = sents[s * LL + tid];
      for (int e = tid; e < WSZF; e += 320) w[e] = 0.f;
      if (tid < 192) feats_u[tid] = 0u;
      __syncthreads();
      for (int e = tid; e < LL * 75; e += 320){
        int l = e / 75, d4 = (e - l * 75) * 4;
        *(float4*)&w[widx(l, d4)] = *(const float4*)&emb[(size_t)ids[l] * DD + d4];
      }
      __syncthreads();
      for (int task = tid; task < 288; task += 320){
        int F  = task / 6;
        int pc = task - F * 6;
        int kk, fbase, colbase; const float* W;
        if (F < 16){ kk = 3; fbase = F * 4;         W = Wc3; colbase = fbase; }
        else if (F < 32){ kk = 4; fbase = (F-16)*4; W = Wc4; colbase = 64 + fbase; }
        else { kk = 5; fbase = (F-32)*4;            W = Wc5; colbase = 128 + fbase; }
        int pos0 = pc * 8;
        float acc[4][8];
        #pragma unroll
        for (int fi = 0; fi < 4; ++fi)
          #pragma unroll
          for (int p = 0; p < 8; ++p) acc[fi][p] = 0.f;
        for (int j = 0; j < kk; ++j){
          const float* wrp = W + (size_t)(fbase * kk + j) * DD;
          int rb[8];
          #pragma unroll
          for (int p = 0; p < 8; ++p) rb[p] = widx(pos0 + p + j, 0);
          for (int d = 0; d < DD; d += 4){
            float4 a[8];
            #pragma unroll
            for (int p = 0; p < 8; ++p) a[p] = *(const float4*)&w[rb[p] + d];
            #pragma unroll
            for (int fi = 0; fi < 4; ++fi){
              float4 wvv = *(const float4*)(wrp + (size_t)fi * kk * DD + d);
              #pragma unroll
              for (int p = 0; p < 8; ++p)
                acc[fi][p] += a[p].x * wvv.x + a[p].y * wvv.y + a[p].z * wvv.z + a[p].w * wvv.w;
            }
          }
        }
        int Pk = LL - kk + 1;
        #pragma unroll
        for (int fi = 0; fi < 4; ++fi){
          float m = -1e30f;
          #pragma unroll
          for (int p = 0; p < 8; ++p) if (pos0 + p < Pk) m = fmaxf(m, acc[fi][p]);
          atomicMax(&feats_u[colbase + fi], fkey(m));
        }
      }
      __syncthreads();
      if (tid < 192){
        float m = funkey(feats_u[tid]);
        float bias = (tid < 64) ? bc3[tid] : ((tid < 128) ? bc4[tid - 64] : bc5[tid - 128]);
        feats_u[tid] = __float_as_uint(fmaxf(0.f, m + bias));
      }
      __syncthreads();
      if (tid < HH){
        float acc = bt[tid];
        for (int c = 0; c < 192; ++c)
          acc += __uint_as_float(feats_u[c]) * Wt[c * HH + tid];
        su[(size_t)s * HH + tid] = ftanh(acc);
      }
      __syncthreads();   // drain su stores (vmcnt) before release RMW
      if (tid == 0){
        u32 old = __hip_atomic_fetch_add(&ctrl[CT_SUC + (s >> 4)], 1u,
                                         __ATOMIC_ACQ_REL, __HIP_MEMORY_SCOPE_AGENT);
        if (old == 15u) st_rel(&ctrl[CT_SUF + (s >> 4)], 1u);
      }
      continue;
    }

    if (jid == 2048){
      // ---- row-0 classifier ----
      wait_ge(&ctrl[CT_SUF + 0], 1u, tid);
      float* tmpf = (float*)(raw + A_SCL);
      if (tid < NCC){
        float acc = bcls[tid];
        for (int h = 0; h < HH; ++h) acc += su[h] * Wcls[h * NCC + tid];
        tmpf[tid] = acc;
      }
      __syncthreads();
      if (tid < NCC){
        float m = tmpf[0];
        #pragma unroll
        for (int c = 1; c < NCC; ++c) m = fmaxf(m, tmpf[c]);
        float ss = 0.f;
        #pragma unroll
        for (int c = 0; c < NCC; ++c) ss += __expf(tmpf[c] - m);
        out[tid] = tmpf[tid] - (m + __logf(ss));
      }
      continue;
    }

    // ---- attention query q + fused classifier ----
    {
      int q = (int)jid - 2049;
      int wmin = 39 - q; if (wmin < 0) wmin = 0;
      wait_ge(&ctrl[CT_SUF + ((q + 1) >> 4)], 1u, tid);
      int clo = ((q >= 39) ? (q - 39) : 0) >> 4;
      int chi = q >> 4;
      for (int c = clo; c <= chi; ++c)
        wait_ge(&ctrl[CT_GM + c], 1u, tid);

      float*    mem_l = (float*)(raw + A_MEML);
      _Float16* mem16 = (_Float16*)(raw + A_MEM16);
      _Float16* g_l   = (_Float16*)(raw + A_GL);
      float*    gh_l  = (float*)(raw + A_GHL);
      float*    bi_l  = (float*)(raw + A_BIL);
      float*    q_l   = (float*)(raw + A_QL);
      float*    hbuf  = (float*)(raw + A_HBUF);
      _Float16* hb16  = (_Float16*)(raw + A_HB16);
      float*    sc_l  = (float*)(raw + A_SCL);
      f16x2 wreg[52];
      float bh = 0.f;

      if (tid < 300){ bi_l[tid] = bih_m[tid]; bh = bhh_m[tid]; }
      if (tid < 104) q_l[tid] = (tid < 100) ? su[(size_t)(q + 1) * HH + tid] : 0.f;
      for (int e = tid; e < 40 * 104; e += 320){
        int w = e / 104, i = e - w * 104;
        float v = 0.f;
        if (i < 100 && w >= wmin) v = hid[(size_t)(q - 39 + w) * HH + i];
        mem_l[e] = v;
        mem16[e] = (_Float16)v;
      }
      for (int e = tid; e < 40 * 300; e += 320){
        int w = e / 300, j = e - w * 300;
        float v = (w >= wmin) ? gmw[(size_t)(q - 39 + w) * 300 + j] : 0.f;
        g_l[e] = (_Float16)v;
      }
      if (tid < 300){
        const float* r0 = Whh_m + (size_t)tid * 100;
        #pragma unroll
        for (int i = 0; i < 25; ++i){
          float4 a = *(const float4*)(r0 + 4 * i);
          wreg[2*i] = pk(a.x, a.y); wreg[2*i+1] = pk(a.z, a.w);
        }
      }
      wreg[50] = pk(0,0); wreg[51] = pk(0,0);
      __syncthreads();

      for (int hop = 0; hop < 3; ++hop){
        if (tid < 40){
          float a0 = 0, a1 = 0, a2 = 0, a3 = 0;
          const float* mr = &mem_l[tid * 104];
          #pragma unroll
          for (int i = 0; i < 25; ++i){
            float4 m4 = *(const float4*)&mr[4 * i];
            float4 q4 = *(const float4*)&q_l[4 * i];
            a0 += m4.x * q4.x; a1 += m4.y * q4.y; a2 += m4.z * q4.z; a3 += m4.w * q4.w;
          }
          sc_l[tid] = (tid >= wmin) ? ((a0 + a1) + (a2 + a3)) : -1e10f;
        }
        __syncthreads();
        if (tid < 64){
          float v = (tid < 40) ? sc_l[tid] : -3e38f;
          float m = v;
          #pragma unroll
          for (int off = 32; off; off >>= 1) m = fmaxf(m, __shfl_xor(m, off));
          float e = (tid < 40) ? __expf(v - m) : 0.f;
          float ssum = e;
          #pragma unroll
          for (int off = 32; off; off >>= 1) ssum += __shfl_xor(ssum, off);
          if (tid < 40) sc_l[tid] = e * frcp(ssum);
        }
        __syncthreads();
        if (tid < 50){
          float c0 = 0.f, c1 = 0.f;
          for (int w = wmin; w < 40; ++w){
            float a = sc_l[w];
            float2 mv = *(const float2*)&mem_l[w * 104 + 2 * tid];
            c0 += a * mv.x; c1 += a * mv.y;
          }
          float q0 = ftanh(q_l[2 * tid]     + c0);
          float q1 = ftanh(q_l[2 * tid + 1] + c1);
          *(float2*)&q_l[2 * tid] = make_float2(q0, q1);
        }
        if (hop == 2) break;

        if (hop == 1){
          if (tid < 300){
            const float* r0 = Wih_m + (size_t)tid * 100;
            #pragma unroll
            for (int i = 0; i < 25; ++i){
              float4 a = *(const float4*)(r0 + 4 * i);
              wreg[2*i] = pk(a.x, a.y); wreg[2*i+1] = pk(a.z, a.w);
            }
            for (int w = 0; w < 40; ++w){
              float a0 = 0, a1 = 0;
              const float4* mq = (const float4*)&mem16[w * 104];
              #pragma unroll
              for (int g = 0; g < 13; ++g){
                float4 hv = mq[g];
                a0 = fdot2(wreg[4*g  ], __builtin_bit_cast(f16x2, hv.x), a0);
                a1 = fdot2(wreg[4*g+1], __builtin_bit_cast(f16x2, hv.y), a1);
                a0 = fdot2(wreg[4*g+2], __builtin_bit_cast(f16x2, hv.z), a0);
                a1 = fdot2(wreg[4*g+3], __builtin_bit_cast(f16x2, hv.w), a1);
              }
              g_l[w * 300 + tid] = (_Float16)(a0 + a1 + bi_l[tid]);
            }
            const float* rh = Whh_m + (size_t)tid * 100;
            #pragma unroll
            for (int i = 0; i < 25; ++i){
              float4 a = *(const float4*)(rh + 4 * i);
              wreg[2*i] = pk(a.x, a.y); wreg[2*i+1] = pk(a.z, a.w);
            }
          }
        }

        if (tid < HH) hbuf[tid] = 0.f;
        if (tid < 104) hb16[tid] = (_Float16)0.f;
        __syncthreads();
        for (int w = 0; w < 40; ++w){
          if (tid < 300){
            float a0 = 0, a1 = 0;
            const float4* hq = (const float4*)hb16;
            #pragma unroll
            for (int g = 0; g < 13; ++g){
              float4 hv = hq[g];
              a0 = fdot2(wreg[4*g  ], __builtin_bit_cast(f16x2, hv.x), a0);
              a1 = fdot2(wreg[4*g+1], __builtin_bit_cast(f16x2, hv.y), a1);
              a0 = fdot2(wreg[4*g+2], __builtin_bit_cast(f16x2, hv.z), a0);
              a1 = fdot2(wreg[4*g+3], __builtin_bit_cast(f16x2, hv.w), a1);
            }
            gh_l[tid] = a0 + a1 + bh;
          }
          __syncthreads();
          if (tid < HH){
            float o = hbuf[tid];
            if (w >= wmin){
              const _Float16* gp = &g_l[w * 300];
              float gir = (float)gp[tid], giz = (float)gp[tid + 100], gin = (float)gp[tid + 200];
              float r = sigm(gir + gh_l[tid]);
              float z = sigm(giz + gh_l[tid + 100]);
              float n = ftanh(gin + r * gh_l[tid + 200]);
              o = (1.f - z) * n + z * o;
            }
            hbuf[tid] = o;
            hb16[tid] = (_Float16)o;
            mem_l[w * 104 + tid] = o;
            mem16[w * 104 + tid] = (_Float16)o;
          }
          __syncthreads();
        }
      }
      __syncthreads();
      if (tid < NCC){
        float acc = bcls[tid];
        for (int h = 0; h < HH; ++h) acc += q_l[h] * Wcls[h * NCC + tid];
        sc_l[tid] = acc;
      }
      __syncthreads();
      if (tid < NCC){
        float m = sc_l[0];
        #pragma unroll
        for (int c = 1; c < NCC; ++c) m = fmaxf(m, sc_l[c]);
        float ss = 0.f;
        #pragma unroll
        for (int c = 0; c < NCC; ++c) ss += __expf(sc_l[c] - m);
        out[(size_t)(q + 1) * NCC + tid] = sc_l[tid] - (m + __logf(ss));
      }
    }
  }
}

extern "C" void kernel_launch(void* const* d_in, const int* in_sizes, int n_in,
                              void* d_out, int out_size, void* d_ws, size_t ws_size,
                              hipStream_t stream)
{
  const int* sents  = (const int*)d_in[0];
  // d_in[1] = lengths (unused by the reference)
  const float* emb    = (const float*)d_in[2];
  const float* Wc3    = (const float*)d_in[3];  const float* bc3 = (const float*)d_in[4];
  const float* Wc4    = (const float*)d_in[5];  const float* bc4 = (const float*)d_in[6];
  const float* Wc5    = (const float*)d_in[7];  const float* bc5 = (const float*)d_in[8];
  const float* Wt     = (const float*)d_in[9];  const float* bt  = (const float*)d_in[10];
  const float* Wih_c  = (const float*)d_in[11]; const float* Whh_c = (const float*)d_in[12];
  const float* bih_c  = (const float*)d_in[13]; const float* bhh_c = (const float*)d_in[14];
  const float* Wih_m  = (const float*)d_in[15]; const float* Whh_m = (const float*)d_in[16];
  const float* bih_m  = (const float*)d_in[17]; const float* bhh_m = (const float*)d_in[18];
  const float* Wcls   = (const float*)d_in[19]; const float* bcls  = (const float*)d_in[20];

  float* ws    = (float*)d_ws;
  float* su    = ws;                  // 2048*100 = 204800
  float* gic   = su  + 204800;        // 2047*300 = 614100
  float* hid   = gic + 614100;        // 2047*100 = 204700
  float* gmw   = hid + 204700;        // 2047*300 = 614100
  u32*   ctrl  = (u32*)(gmw + 614100);// 1024 u32 control region

  hipMemsetAsync((void*)ctrl, 0, 4096, stream);
  k_fused<<<256, 320, 0, stream>>>(sents, emb,
                                   Wc3, bc3, Wc4, bc4, Wc5, bc5, Wt, bt,
                                   su, gic, hid, gmw, ctrl,
                                   Wih_c, bih_c, Whh_c, bhh_c,
                                   Wih_m, bih_m, Whh_m, bhh_m,
                                   Wcls, bcls, (float*)d_out);
}